// Round 10
// baseline (889.900 us; speedup 1.0000x reference)
//
#include <hip/hip_runtime.h>
#include <cstddef>

// Problem constants
#define BB 32
#define NN 128
#define PP 8128

typedef __attribute__((ext_vector_type(8))) short short8;
typedef __attribute__((ext_vector_type(4))) float floatx4;

union U4S8 { uint4 u; short8 s; };
__device__ __forceinline__ short8 as_s8(uint4 v){ U4S8 x; x.u = v; return x.s; }

// ---------- bf16 helpers ----------
__device__ __forceinline__ float bf_lo(unsigned u){ union{unsigned v;float f;}x; x.v=u<<16; return x.f; }
__device__ __forceinline__ float bf_hi(unsigned u){ union{unsigned v;float f;}x; x.v=u&0xffff0000u; return x.f; }
__device__ __forceinline__ unsigned pack_bf16(float a, float b){
  union{float f;unsigned u;}xa,xb; xa.f=a; xb.f=b;
  unsigned ua=xa.u, ub=xb.u;
  ua = (ua + 0x7fffu + ((ua>>16)&1u)) >> 16;
  ub = (ub + 0x7fffu + ((ub>>16)&1u)) >> 16;
  return (ua & 0xffffu) | (ub << 16);
}
__device__ __forceinline__ unsigned short bf16_1(float a){
  union{float f;unsigned u;}x; x.f=a;
  return (unsigned short)((x.u + 0x7fffu + ((x.u>>16)&1u)) >> 16);
}
__device__ __forceinline__ float sigf(float x){ return 1.f/(1.f + __expf(-x)); }

// ---------- weight conversion + round-0 tables ----------
__global__ __launch_bounds__(256,4) void conv_w_kernel(
  const float* __restrict__ Wl_e, const float* __restrict__ Wm_e,
  const float* __restrict__ Wu_e, const float* __restrict__ Wu_m,
  const float* __restrict__ Wr1, const float* __restrict__ Wr2,
  const float* __restrict__ emb,
  unsigned* __restrict__ wT, unsigned* __restrict__ wr1T,
  unsigned* __restrict__ wr2T,
  float* __restrict__ embZ, float* __restrict__ embM, float* __restrict__ embU)
{
  int tid = blockIdx.x*256 + threadIdx.x;   // 65536 total
  if (tid < 2048) {   // Wr2 [256][10] -> B-frag layout [16 cols][128 k2], zero-padded
    int c = tid >> 7, k2 = tid & 127;
    unsigned v = 0;
    if (c < 10) v = pack_bf16(Wr2[(2*k2)*10 + c], Wr2[(2*k2+1)*10 + c]);
    wr2T[c*128 + k2] = v;
  }
  if (tid >= 4096 && tid < 5632) {   // round-0 tables: emb(4x128) @ W(128x128), f32
    int idx = tid - 4096;            // 0..1535
    int tb = idx >> 9;               // 0..2
    int r  = idx & 511;
    int id = r >> 7, c = r & 127;
    const float* W = (tb==0) ? Wl_e : (tb==1) ? Wm_e : Wu_e;
    float s = 0.f;
    #pragma unroll 4
    for (int k = 0; k < 128; ++k) s += emb[id*128 + k] * W[(size_t)k*128 + c];
    float* T = (tb==0) ? embZ : (tb==1) ? embM : embU;
    T[r] = s;
  }
  if (tid < 32768) {
    int mat = tid >> 13, r = tid & 8191;
    int k2 = r >> 7, c = r & 127;
    const float* W = (mat==0) ? Wl_e : (mat==1) ? Wm_e : (mat==2) ? Wu_e : Wu_m;
    wT[mat*8192 + c*64 + k2] = pack_bf16(W[(2*k2)*128 + c], W[(2*k2+1)*128 + c]);
  } else {
    int r = tid - 32768;
    int k2 = r >> 8, c = r & 255;
    wr1T[(size_t)c*128 + k2] = pack_bf16(Wr1[(2*k2)*256 + c], Wr1[(2*k2+1)*256 + c]);
  }
}

// ---------- fused GRU + node projections ----------
__global__ __launch_bounds__(256,4) void gru_proj_kernel(
  int do_gru,
  const float* __restrict__ ms, const float* __restrict__ h_in, float* __restrict__ h_out,
  const float* __restrict__ W_ih, const float* __restrict__ W_hh,
  const float* __restrict__ b_ih, const float* __restrict__ b_hh,
  const float* __restrict__ Wl_w, const float* __restrict__ Wl_v,
  const float* __restrict__ Wm_w, const float* __restrict__ Wm_v,
  const int* __restrict__ event_nums,
  float* __restrict__ a_l, float* __restrict__ b_l,
  float* __restrict__ a_m, float* __restrict__ b_m)
{
  __shared__ float h_s[4][128];
  __shared__ float ms_s[4][128];
  const int t = threadIdx.x, blk = blockIdx.x;
  const int b = blk >> 5, n0 = (blk & 31) * 4;
  const int vn = event_nums[b];
  const int g = t >> 6, l = t & 63;
  const int row = b*128 + n0 + g;

  h_s[g][l]    = h_in[(size_t)row*128 + l];
  h_s[g][l+64] = h_in[(size_t)row*128 + l + 64];
  if (do_gru) {
    ms_s[g][l]    = ms[(size_t)row*128 + l];
    ms_s[g][l+64] = ms[(size_t)row*128 + l + 64];
  }
  __syncthreads();

  if (do_gru) {
    float acc[12] = {};
    #pragma unroll 4
    for (int k = 0; k < 128; ++k) {
      float mv = ms_s[g][k], hv = h_s[g][k];
      #pragma unroll
      for (int u = 0; u < 6; ++u) {
        acc[u]   += mv * W_ih[(size_t)k*384 + l + 64*u];
        acc[6+u] += hv * W_hh[(size_t)k*384 + l + 64*u];
      }
    }
    const bool valid = (n0 + g) < vn;
    float hnew[2];
    #pragma unroll
    for (int u = 0; u < 2; ++u) {
      int c = l + 64*u;
      float ir = acc[u]     + b_ih[c];
      float iz = acc[u+2]   + b_ih[128+c];
      float in_= acc[u+4]   + b_ih[256+c];
      float hr = acc[6+u]   + b_hh[c];
      float hz = acc[8+u]   + b_hh[128+c];
      float hn = acc[10+u]  + b_hh[256+c];
      float r  = sigf(ir + hr);
      float zg = sigf(iz + hz);
      float nn = tanhf(in_ + r*hn);
      float hold = h_s[g][c];
      hnew[u] = valid ? (1.f - zg)*nn + zg*hold : hold;
    }
    __syncthreads();
    #pragma unroll
    for (int u = 0; u < 2; ++u) {
      int c = l + 64*u;
      h_s[g][c] = hnew[u];
      h_out[(size_t)row*128 + c] = hnew[u];
    }
    __syncthreads();
  }

  {
    const float* Wp[4] = {Wl_w, Wl_v, Wm_w, Wm_v};
    float* Op[4] = {a_l, b_l, a_m, b_m};
    float acc2[8] = {};
    #pragma unroll 4
    for (int k = 0; k < 128; ++k) {
      float hv = h_s[g][k];
      #pragma unroll
      for (int u = 0; u < 8; ++u)
        acc2[u] += hv * Wp[u>>1][(size_t)k*128 + l + 64*(u&1)];
    }
    #pragma unroll
    for (int u = 0; u < 8; ++u)
      Op[u>>1][(size_t)row*128 + l + 64*(u&1)] = acc2[u];
  }
}

// ---------- MFMA edge-round kernel: fused single E-pass, 64-row half-blocks ----------
// grid = B*N*2 (one workgroup per (b,j,rowhalf)), block 256 = 4 waves in 2x2.
// Rounds>=1: ONE fused K-pass computes Z, M0, Ue (3 accs = 96 AGPR + ~55 VGPR, no spill
// at launch_bounds(256,3)). Round 0: E-GEMMs replaced by f32 table gathers (E rows are
// one of 4 emb vectors) — only the M@Wu_m MFMA pass runs.
__global__ __launch_bounds__(256,3) void edge_round_mfma(
  unsigned* __restrict__ eg,           // [B][N(j)][N(i)][64] bf16-pairs
  const unsigned* __restrict__ wT,     // [Wl_e|Wm_e|Wu_e|Wu_m] each [c][64] bf16-pairs
  const int* __restrict__ ids,         // [B][N][N]
  int first,
  const float* __restrict__ embZ, const float* __restrict__ embM,
  const float* __restrict__ embU,      // [4][128] f32 tables (emb @ W)
  const float* __restrict__ a_l, const float* __restrict__ b_l,
  const float* __restrict__ a_m, const float* __restrict__ b_m,
  const float* __restrict__ bl1, const float* __restrict__ wl2,
  const float* __restrict__ bl2, const float* __restrict__ bm,
  const float* __restrict__ bu,
  const int* __restrict__ event_nums,
  float* __restrict__ ms)              // [B][N][128], pre-zeroed, accumulated atomically
{
  __shared__ unsigned m_a[64*68];    // m (later u) as bf16, padded rows
  __shared__ float adj[64], svec[64], msum[128];
  __shared__ float bL_s[128], bM_s[128], bu_s[128], wl2_s[128];
  __shared__ float tabZ[512], tabM[512], tabU[512];
  __shared__ int id_s[64];
  unsigned short* m16 = (unsigned short*)m_a;

  const int t = threadIdx.x;
  const int b = blockIdx.x >> 8, j = (blockIdx.x >> 1) & 127, half = blockIdx.x & 1;
  const int vn = event_nums[b];
  const int row0 = half*64;
  int vnl = vn - row0; vnl = vnl < 0 ? 0 : (vnl > 64 ? 64 : vnl);

  if (j >= vn || vnl == 0) return;   // fully invalid: ms pre-zeroed, eg untouched

  unsigned* eblk = eg + (size_t)(b*128 + j) * 8192;
  const bool fst = (first != 0);

  if (t < 128) {
    bL_s[t] = b_l[(size_t)(b*128 + j)*128 + t] + bl1[t];
    bM_s[t] = b_m[(size_t)(b*128 + j)*128 + t] + bm[t];
    bu_s[t] = bu[t];
    wl2_s[t] = wl2[t];
    msum[t] = 0.f;
  }
  if (t < 64) {
    adj[t] = 0.f;
    if (fst) id_s[t] = ids[((size_t)(b*128 + row0 + t))*128 + j];
  }
  if (fst) {
    for (int i = t; i < 512; i += 256) {
      tabZ[i] = embZ[i]; tabM[i] = embM[i]; tabU[i] = embU[i];
    }
  }
  __syncthreads();

  const int lane = t & 63, wv = t >> 6;
  const int q = lane >> 4, n = lane & 15;
  const int rh2 = wv >> 1, ch = wv & 1;

  int nvt = (vnl - rh2*32 + 15) >> 4;
  nvt = nvt < 0 ? 0 : (nvt > 2 ? 2 : nvt);

  const unsigned* wz  = wT;
  const unsigned* wm  = wT + 8192;
  const unsigned* wue = wT + 16384;
  const unsigned* wum = wT + 24576;

  int colg[4];
  #pragma unroll
  for (int ct = 0; ct < 4; ++ct) colg[ct] = ch*64 + ct*16 + n;

  int arowi[2];
  #pragma unroll
  for (int rt = 0; rt < 2; ++rt) arowi[rt] = rh2*32 + rt*16 + n;

  // ---------- fused single K-pass: Z = E@Wl_e, M0 = E@Wm_e, Ue = E@Wu_e ----------
  floatx4 az[2][4], am2[2][4], au[2][4];
  #pragma unroll
  for (int rt = 0; rt < 2; ++rt)
    #pragma unroll
    for (int ct = 0; ct < 4; ++ct) {
      az[rt][ct]  = (floatx4){0.f,0.f,0.f,0.f};
      am2[rt][ct] = (floatx4){0.f,0.f,0.f,0.f};
      au[rt][ct]  = (floatx4){0.f,0.f,0.f,0.f};
    }
  if (!fst) {
    #pragma unroll
    for (int kb = 0; kb < 4; ++kb) {
      uint4 a[2];
      #pragma unroll
      for (int rt = 0; rt < 2; ++rt)
        if (rt < nvt) a[rt] = *(const uint4*)&eblk[(size_t)(row0 + arowi[rt])*64 + kb*16 + q*4];
      uint4 bb[4];
      #pragma unroll
      for (int ct = 0; ct < 4; ++ct) bb[ct] = *(const uint4*)(wz + colg[ct]*64 + kb*16 + q*4);
      #pragma unroll
      for (int rt = 0; rt < 2; ++rt)
        if (rt < nvt)
          #pragma unroll
          for (int ct = 0; ct < 4; ++ct)
            az[rt][ct] = __builtin_amdgcn_mfma_f32_16x16x32_bf16(as_s8(a[rt]), as_s8(bb[ct]), az[rt][ct], 0, 0, 0);
      #pragma unroll
      for (int ct = 0; ct < 4; ++ct) bb[ct] = *(const uint4*)(wm + colg[ct]*64 + kb*16 + q*4);
      #pragma unroll
      for (int rt = 0; rt < 2; ++rt)
        if (rt < nvt)
          #pragma unroll
          for (int ct = 0; ct < 4; ++ct)
            am2[rt][ct] = __builtin_amdgcn_mfma_f32_16x16x32_bf16(as_s8(a[rt]), as_s8(bb[ct]), am2[rt][ct], 0, 0, 0);
      #pragma unroll
      for (int ct = 0; ct < 4; ++ct) bb[ct] = *(const uint4*)(wue + colg[ct]*64 + kb*16 + q*4);
      #pragma unroll
      for (int rt = 0; rt < 2; ++rt)
        if (rt < nvt)
          #pragma unroll
          for (int ct = 0; ct < 4; ++ct)
            au[rt][ct] = __builtin_amdgcn_mfma_f32_16x16x32_bf16(as_s8(a[rt]), as_s8(bb[ct]), au[rt][ct], 0, 0, 0);
    }
  }

  // ---------- Z epilogue: adj[row] += sum_col relu(z + a_l + bL) * wl2 ----------
  {
    float wl2v[4], bLv[4];
    #pragma unroll
    for (int ct = 0; ct < 4; ++ct) { wl2v[ct] = wl2_s[colg[ct]]; bLv[ct] = bL_s[colg[ct]]; }
    #pragma unroll
    for (int rt = 0; rt < 2; ++rt) {
      if (rt < nvt) {
        float szr[4] = {0.f,0.f,0.f,0.f};
        #pragma unroll
        for (int ct = 0; ct < 4; ++ct) {
          #pragma unroll
          for (int r = 0; r < 4; ++r) {
            int lrow = rh2*32 + rt*16 + q*4 + r;
            float zraw = fst ? tabZ[id_s[lrow]*128 + colg[ct]] : az[rt][ct][r];
            float al = a_l[(size_t)(b*128 + row0 + lrow)*128 + colg[ct]];
            float zv = fmaxf(zraw + al + bLv[ct], 0.f);
            szr[r] += zv * wl2v[ct];
          }
        }
        #pragma unroll
        for (int r = 0; r < 4; ++r) {
          szr[r] += __shfl_xor(szr[r], 1);
          szr[r] += __shfl_xor(szr[r], 2);
          szr[r] += __shfl_xor(szr[r], 4);
          szr[r] += __shfl_xor(szr[r], 8);
        }
        if (n == 0) {
          #pragma unroll
          for (int r = 0; r < 4; ++r)
            atomicAdd(&adj[rh2*32 + rt*16 + q*4 + r], szr[r]);
        }
      }
    }
  }
  __syncthreads();
  if (t < 64) svec[t] = sigf(adj[t] + bl2[0]);
  __syncthreads();

  // ---------- M epilogue: m = relu(m0 + a_m + bM) * svec (masked) -> m16; colsum -> msum ----------
  {
    float bMv[4];
    #pragma unroll
    for (int ct = 0; ct < 4; ++ct) bMv[ct] = bM_s[colg[ct]];
    float colsum[4] = {0.f,0.f,0.f,0.f};
    #pragma unroll
    for (int rt = 0; rt < 2; ++rt) {
      if (rt < nvt) {
        #pragma unroll
        for (int ct = 0; ct < 4; ++ct) {
          #pragma unroll
          for (int r = 0; r < 4; ++r) {
            int lrow = rh2*32 + rt*16 + q*4 + r;
            float mraw = fst ? tabM[id_s[lrow]*128 + colg[ct]] : am2[rt][ct][r];
            float am = a_m[(size_t)(b*128 + row0 + lrow)*128 + colg[ct]];
            float mv = fmaxf(mraw + am + bMv[ct], 0.f);
            float sc = (lrow < vnl) ? svec[lrow] : 0.f;
            mv *= sc;
            m16[lrow*136 + colg[ct]] = bf16_1(mv);
            colsum[ct] += mv;
          }
        }
      }
    }
    #pragma unroll
    for (int ct = 0; ct < 4; ++ct) {
      float v = colsum[ct];
      v += __shfl_xor(v, 16);
      v += __shfl_xor(v, 32);
      if (lane < 16) atomicAdd(&msum[colg[ct]], v);
    }
  }
  __syncthreads();
  if (t < 128) atomicAdd(&ms[(size_t)(b*128 + j)*128 + t], msum[t]);

  // ---------- round 0: au starts from Ue table gather ----------
  if (fst) {
    #pragma unroll
    for (int rt = 0; rt < 2; ++rt)
      if (rt < nvt)
        #pragma unroll
        for (int ct = 0; ct < 4; ++ct)
          #pragma unroll
          for (int r = 0; r < 4; ++r) {
            int lrow = rh2*32 + rt*16 + q*4 + r;
            au[rt][ct][r] = tabU[id_s[lrow]*128 + colg[ct]];
          }
  }

  // ---------- Um pass: U += M @ Wu_m (M resident in LDS) ----------
  #pragma unroll
  for (int kb = 0; kb < 4; ++kb) {
    uint4 bb[4];
    #pragma unroll
    for (int ct = 0; ct < 4; ++ct) bb[ct] = *(const uint4*)(wum + colg[ct]*64 + kb*16 + q*4);
    #pragma unroll
    for (int rt = 0; rt < 2; ++rt) {
      if (rt < nvt) {
        uint4 a = *(const uint4*)&m_a[arowi[rt]*68 + kb*16 + q*4];
        #pragma unroll
        for (int ct = 0; ct < 4; ++ct)
          au[rt][ct] = __builtin_amdgcn_mfma_f32_16x16x32_bf16(as_s8(a), as_s8(bb[ct]), au[rt][ct], 0, 0, 0);
      }
    }
  }
  __syncthreads();   // all m_a reads done before overwrite

  {
    float buv[4];
    #pragma unroll
    for (int ct = 0; ct < 4; ++ct) buv[ct] = bu_s[colg[ct]];
    #pragma unroll
    for (int rt = 0; rt < 2; ++rt) {
      if (rt < nvt) {
        #pragma unroll
        for (int ct = 0; ct < 4; ++ct)
          #pragma unroll
          for (int r = 0; r < 4; ++r) {
            int lrow = rh2*32 + rt*16 + q*4 + r;
            m16[lrow*136 + colg[ct]] = bf16_1(fmaxf(au[rt][ct][r] + buv[ct], 0.f));
          }
      }
    }
  }
  __syncthreads();
  #pragma unroll
  for (int it = 0; it < 16; ++it) {
    int f = it*256 + t;
    int lr = f >> 6, c2 = f & 63;
    if (row0 + lr < vn) eblk[(size_t)(row0 + lr)*64 + c2] = m_a[lr*68 + c2];
  }
}

// ---------- MFMA readout, both GEMMs on matrix cores ----------
__global__ __launch_bounds__(256,4) void readout_mfma(
  const unsigned* __restrict__ eg,
  const unsigned* __restrict__ wr1T,   // [256 cols][128 k2] bf16-pairs
  const unsigned* __restrict__ wr2T,   // [16 cols][128 k2] bf16-pairs (cols 10..15 zero)
  const float* __restrict__ br1, const float* __restrict__ br2,
  const int* __restrict__ event_nums, float* __restrict__ out)
{
  __shared__ unsigned f_s[64*132];     // feat bf16 pairs, padded rows; reused as h16
  __shared__ int iu_s[64], ju_s[64];
  unsigned short* h16 = (unsigned short*)f_s;   // overlay: 64 rows x 264 halves

  const int t = threadIdx.x;
  const int b = blockIdx.x / 127, pb = blockIdx.x % 127;
  const int vn = event_nums[b];

  if (t < 64) {
    int p = pb*64 + t;
    float disc = (float)((2*NN-1)*(2*NN-1) - 8*p);
    int iu = (int)(((float)(2*NN-1) - sqrtf(disc)) * 0.5f);
    if (iu < 0) iu = 0; if (iu > NN-2) iu = NN-2;
    while (iu < NN-2 && ((iu+1)*(2*NN-2-iu))/2 <= p) ++iu;
    while (iu > 0 && (iu*(2*NN-1-iu))/2 > p) --iu;
    int ju = p - (iu*(2*NN-1-iu))/2 + iu + 1;
    iu_s[t] = iu; ju_s[t] = ju;
  }
  __syncthreads();

  #pragma unroll
  for (int it = 0; it < 32; ++it) {
    int f = it*256 + t;
    int pr = f >> 7, w = f & 127;
    int side = w >> 6, k2l = w & 63;
    int iu = iu_s[pr], ju = ju_s[pr];
    size_t base = side ? (((size_t)(b*128 + iu))*128 + ju)*64
                       : (((size_t)(b*128 + ju))*128 + iu)*64;
    f_s[pr*132 + w] = eg[base + k2l];
  }
  __syncthreads();

  const int lane = t & 63, wv = t >> 6;
  const int q = lane >> 4, n = lane & 15;
  int colg[4];
  #pragma unroll
  for (int ct = 0; ct < 4; ++ct) colg[ct] = wv*64 + ct*16 + n;

  floatx4 acc[4][4];
  #pragma unroll
  for (int rt = 0; rt < 4; ++rt)
    #pragma unroll
    for (int ct = 0; ct < 4; ++ct) acc[rt][ct] = (floatx4){0.f,0.f,0.f,0.f};

  #pragma unroll
  for (int kb = 0; kb < 8; ++kb) {
    uint4 bb[4];
    #pragma unroll
    for (int ct = 0; ct < 4; ++ct) bb[ct] = *(const uint4*)(wr1T + (size_t)colg[ct]*128 + kb*16 + q*4);
    #pragma unroll
    for (int rt = 0; rt < 4; ++rt) {
      uint4 a = *(const uint4*)&f_s[(rt*16 + n)*132 + kb*16 + q*4];
      #pragma unroll
      for (int ct = 0; ct < 4; ++ct)
        acc[rt][ct] = __builtin_amdgcn_mfma_f32_16x16x32_bf16(as_s8(a), as_s8(bb[ct]), acc[rt][ct], 0, 0, 0);
    }
  }
  __syncthreads();

  {
    float brv[4];
    #pragma unroll
    for (int ct = 0; ct < 4; ++ct) brv[ct] = br1[colg[ct]];
    #pragma unroll
    for (int rt = 0; rt < 4; ++rt)
      #pragma unroll
      for (int ct = 0; ct < 4; ++ct)
        #pragma unroll
        for (int r = 0; r < 4; ++r) {
          int pr = rt*16 + q*4 + r;
          h16[pr*264 + colg[ct]] = bf16_1(fmaxf(acc[rt][ct][r] + brv[ct], 0.f));
        }
  }
  __syncthreads();

  floatx4 acc2 = (floatx4){0.f,0.f,0.f,0.f};
  #pragma unroll
  for (int kb = 0; kb < 8; ++kb) {
    uint4 bb = *(const uint4*)(wr2T + n*128 + kb*16 + q*4);
    uint4 a  = *(const uint4*)&f_s[(wv*16 + n)*132 + kb*16 + q*4];
    acc2 = __builtin_amdgcn_mfma_f32_16x16x32_bf16(as_s8(a), as_s8(bb), acc2, 0, 0, 0);
  }

  if (n < 10) {
    float bias = br2[n];
    #pragma unroll
    for (int r = 0; r < 4; ++r) {
      int pr = wv*16 + q*4 + r;
      int iu = iu_s[pr], ju = ju_s[pr];
      if (ju < vn) {
        int idx = iu*vn - (iu*(iu+1))/2 + (ju - iu - 1);
        out[(((size_t)b*5 + (n>>1))*PP + idx)*2 + (n&1)] = acc2[r] + bias;
      }
    }
  }
}

extern "C" void kernel_launch(void* const* d_in, const int* in_sizes, int n_in,
                              void* d_out, int out_size, void* d_ws, size_t ws_size,
                              hipStream_t stream) {
  const int*   edge_ids      = (const int*)d_in[0];
  const float* node_features = (const float*)d_in[1];
  const int*   event_nums    = (const int*)d_in[3];
  const float* emb  = (const float*)d_in[4];
  const float* Wl_e = (const float*)d_in[5];
  const float* Wl_w = (const float*)d_in[6];
  const float* Wl_v = (const float*)d_in[7];
  const float* bl1  = (const float*)d_in[8];
  const float* wl2  = (const float*)d_in[9];
  const float* bl2  = (const float*)d_in[10];
  const float* Wm_w = (const float*)d_in[11];
  const float* Wm_v = (const float*)d_in[12];
  const float* Wm_e = (const float*)d_in[13];
  const float* bm   = (const float*)d_in[14];
  const float* Wu_e = (const float*)d_in[15];
  const float* Wu_m = (const float*)d_in[16];
  const float* bu   = (const float*)d_in[17];
  const float* W_ih = (const float*)d_in[18];
  const float* W_hh = (const float*)d_in[19];
  const float* b_ih = (const float*)d_in[20];
  const float* b_hh = (const float*)d_in[21];
  const float* Wr1  = (const float*)d_in[22];
  const float* br1  = (const float*)d_in[23];
  const float* Wr2  = (const float*)d_in[24];
  const float* br2  = (const float*)d_in[25];

  const size_t SZ_E = (size_t)134217728;       // B*N*N*64 u32
  const size_t SZ_S = (size_t)2097152;         // B*N*128 f32
  const size_t SZ_W = (size_t)131072;          // 32768 u32
  const size_t SZ_W2 = (size_t)8192;           // 2048 u32
  const size_t SZ_TAB = (size_t)2048;          // 512 f32 each
  const size_t need = SZ_E + 6*SZ_S + 2*SZ_W + SZ_W2 + 3*SZ_TAB;

  hipMemsetAsync(d_out, 0, (size_t)out_size * sizeof(float), stream);
  if (ws_size < need) return;   // clean failure instead of OOB fault

  char* w = (char*)d_ws;
  unsigned* eg   = (unsigned*)w; w += SZ_E;
  float* h_ws = (float*)w; w += SZ_S;
  float* a_l  = (float*)w; w += SZ_S;
  float* b_l  = (float*)w; w += SZ_S;
  float* a_m  = (float*)w; w += SZ_S;
  float* b_m  = (float*)w; w += SZ_S;
  float* ms   = (float*)w; w += SZ_S;
  unsigned* wT   = (unsigned*)w; w += SZ_W;
  unsigned* wr1T = (unsigned*)w; w += SZ_W;
  unsigned* wr2T = (unsigned*)w; w += SZ_W2;
  float* embZ = (float*)w; w += SZ_TAB;
  float* embM = (float*)w; w += SZ_TAB;
  float* embU = (float*)w; w += SZ_TAB;

  hipLaunchKernelGGL(conv_w_kernel, dim3(256), dim3(256), 0, stream,
      Wl_e, Wm_e, Wu_e, Wu_m, Wr1, Wr2, emb, wT, wr1T, wr2T, embZ, embM, embU);

  hipLaunchKernelGGL(gru_proj_kernel, dim3(1024), dim3(256), 0, stream,
      0, ms, node_features, h_ws, W_ih, W_hh, b_ih, b_hh,
      Wl_w, Wl_v, Wm_w, Wm_v, event_nums, a_l, b_l, a_m, b_m);

  for (int r = 0; r < 3; ++r) {
    hipMemsetAsync(ms, 0, SZ_S, stream);   // ms accumulated atomically by edge kernel
    hipLaunchKernelGGL(edge_round_mfma, dim3(8192), dim3(256), 0, stream,
        eg, wT, edge_ids, (r == 0) ? 1 : 0, embZ, embM, embU,
        a_l, b_l, a_m, b_m, bl1, wl2, bl2, bm, bu, event_nums, ms);
    if (r < 2) {
      const float* hin = (r == 0) ? node_features : h_ws;
      hipLaunchKernelGGL(gru_proj_kernel, dim3(1024), dim3(256), 0, stream,
          1, ms, hin, h_ws, W_ih, W_hh, b_ih, b_hh,
          Wl_w, Wl_v, Wm_w, Wm_v, event_nums, a_l, b_l, a_m, b_m);
    }
  }

  hipLaunchKernelGGL(readout_mfma, dim3(BB*127), dim3(256), 0, stream,
      eg, wr1T, wr2T, br1, br2, event_nums, (float*)d_out);
}

// Round 11
// 818.347 us; speedup vs baseline: 1.0874x; 1.0874x over previous
//
#include <hip/hip_runtime.h>
#include <cstddef>

// Problem constants
#define BB 32
#define NN 128
#define PP 8128

typedef __attribute__((ext_vector_type(8))) short short8;
typedef __attribute__((ext_vector_type(4))) float floatx4;

union U4S8 { uint4 u; short8 s; };
__device__ __forceinline__ short8 as_s8(uint4 v){ U4S8 x; x.u = v; return x.s; }

// ---------- bf16 helpers ----------
__device__ __forceinline__ float bf_lo(unsigned u){ union{unsigned v;float f;}x; x.v=u<<16; return x.f; }
__device__ __forceinline__ float bf_hi(unsigned u){ union{unsigned v;float f;}x; x.v=u&0xffff0000u; return x.f; }
__device__ __forceinline__ unsigned pack_bf16(float a, float b){
  union{float f;unsigned u;}xa,xb; xa.f=a; xb.f=b;
  unsigned ua=xa.u, ub=xb.u;
  ua = (ua + 0x7fffu + ((ua>>16)&1u)) >> 16;
  ub = (ub + 0x7fffu + ((ub>>16)&1u)) >> 16;
  return (ua & 0xffffu) | (ub << 16);
}
__device__ __forceinline__ unsigned short bf16_1(float a){
  union{float f;unsigned u;}x; x.f=a;
  return (unsigned short)((x.u + 0x7fffu + ((x.u>>16)&1u)) >> 16);
}
__device__ __forceinline__ float sigf(float x){ return 1.f/(1.f + __expf(-x)); }

// ---------- weight conversion + round-0 tables ----------
__global__ __launch_bounds__(256,4) void conv_w_kernel(
  const float* __restrict__ Wl_e, const float* __restrict__ Wm_e,
  const float* __restrict__ Wu_e, const float* __restrict__ Wu_m,
  const float* __restrict__ Wr1, const float* __restrict__ Wr2,
  const float* __restrict__ emb,
  unsigned* __restrict__ wT, unsigned* __restrict__ wr1T,
  unsigned* __restrict__ wr2T,
  float* __restrict__ embZ, float* __restrict__ embM, float* __restrict__ embU)
{
  int tid = blockIdx.x*256 + threadIdx.x;   // 65536 total
  if (tid < 2048) {   // Wr2 [256][10] -> B-frag layout [16 cols][128 k2], zero-padded
    int c = tid >> 7, k2 = tid & 127;
    unsigned v = 0;
    if (c < 10) v = pack_bf16(Wr2[(2*k2)*10 + c], Wr2[(2*k2+1)*10 + c]);
    wr2T[c*128 + k2] = v;
  }
  if (tid >= 4096 && tid < 5632) {   // round-0 tables: emb(4x128) @ W(128x128), f32
    int idx = tid - 4096;            // 0..1535
    int tb = idx >> 9;               // 0..2
    int r  = idx & 511;
    int id = r >> 7, c = r & 127;
    const float* W = (tb==0) ? Wl_e : (tb==1) ? Wm_e : Wu_e;
    float s = 0.f;
    #pragma unroll 4
    for (int k = 0; k < 128; ++k) s += emb[id*128 + k] * W[(size_t)k*128 + c];
    float* T = (tb==0) ? embZ : (tb==1) ? embM : embU;
    T[r] = s;
  }
  if (tid < 32768) {
    int mat = tid >> 13, r = tid & 8191;
    int k2 = r >> 7, c = r & 127;
    const float* W = (mat==0) ? Wl_e : (mat==1) ? Wm_e : (mat==2) ? Wu_e : Wu_m;
    wT[mat*8192 + c*64 + k2] = pack_bf16(W[(2*k2)*128 + c], W[(2*k2+1)*128 + c]);
  } else {
    int r = tid - 32768;
    int k2 = r >> 8, c = r & 255;
    wr1T[(size_t)c*128 + k2] = pack_bf16(Wr1[(2*k2)*256 + c], Wr1[(2*k2+1)*256 + c]);
  }
}

// ---------- fused GRU + node projections ----------
__global__ __launch_bounds__(256,4) void gru_proj_kernel(
  int do_gru,
  const float* __restrict__ ms, const float* __restrict__ h_in, float* __restrict__ h_out,
  const float* __restrict__ W_ih, const float* __restrict__ W_hh,
  const float* __restrict__ b_ih, const float* __restrict__ b_hh,
  const float* __restrict__ Wl_w, const float* __restrict__ Wl_v,
  const float* __restrict__ Wm_w, const float* __restrict__ Wm_v,
  const int* __restrict__ event_nums,
  float* __restrict__ a_l, float* __restrict__ b_l,
  float* __restrict__ a_m, float* __restrict__ b_m)
{
  __shared__ float h_s[4][128];
  __shared__ float ms_s[4][128];
  const int t = threadIdx.x, blk = blockIdx.x;
  const int b = blk >> 5, n0 = (blk & 31) * 4;
  const int vn = event_nums[b];
  const int g = t >> 6, l = t & 63;
  const int row = b*128 + n0 + g;

  h_s[g][l]    = h_in[(size_t)row*128 + l];
  h_s[g][l+64] = h_in[(size_t)row*128 + l + 64];
  if (do_gru) {
    ms_s[g][l]    = ms[(size_t)row*128 + l];
    ms_s[g][l+64] = ms[(size_t)row*128 + l + 64];
  }
  __syncthreads();

  if (do_gru) {
    float acc[12] = {};
    #pragma unroll 4
    for (int k = 0; k < 128; ++k) {
      float mv = ms_s[g][k], hv = h_s[g][k];
      #pragma unroll
      for (int u = 0; u < 6; ++u) {
        acc[u]   += mv * W_ih[(size_t)k*384 + l + 64*u];
        acc[6+u] += hv * W_hh[(size_t)k*384 + l + 64*u];
      }
    }
    const bool valid = (n0 + g) < vn;
    float hnew[2];
    #pragma unroll
    for (int u = 0; u < 2; ++u) {
      int c = l + 64*u;
      float ir = acc[u]     + b_ih[c];
      float iz = acc[u+2]   + b_ih[128+c];
      float in_= acc[u+4]   + b_ih[256+c];
      float hr = acc[6+u]   + b_hh[c];
      float hz = acc[8+u]   + b_hh[128+c];
      float hn = acc[10+u]  + b_hh[256+c];
      float r  = sigf(ir + hr);
      float zg = sigf(iz + hz);
      float nn = tanhf(in_ + r*hn);
      float hold = h_s[g][c];
      hnew[u] = valid ? (1.f - zg)*nn + zg*hold : hold;
    }
    __syncthreads();
    #pragma unroll
    for (int u = 0; u < 2; ++u) {
      int c = l + 64*u;
      h_s[g][c] = hnew[u];
      h_out[(size_t)row*128 + c] = hnew[u];
    }
    __syncthreads();
  }

  {
    const float* Wp[4] = {Wl_w, Wl_v, Wm_w, Wm_v};
    float* Op[4] = {a_l, b_l, a_m, b_m};
    float acc2[8] = {};
    #pragma unroll 4
    for (int k = 0; k < 128; ++k) {
      float hv = h_s[g][k];
      #pragma unroll
      for (int u = 0; u < 8; ++u)
        acc2[u] += hv * Wp[u>>1][(size_t)k*128 + l + 64*(u&1)];
    }
    #pragma unroll
    for (int u = 0; u < 8; ++u)
      Op[u>>1][(size_t)row*128 + l + 64*(u&1)] = acc2[u];
  }
}

// ---------- MFMA edge-round kernel: 3 passes, hoisted loads, 64-row half-blocks ----------
// grid = B*N*2, block 256 = 4 waves in 2x2 (rowquarter x colhalf).
// ILP fix: all 16 B-frag loads per pass hoisted to registers before the MFMA chain;
// epilogue operands (a_l/a_m, 32 scalars) prefetched before/overlapping passes.
// Round 0: E-side GEMMs replaced by f32 table gathers. 5 barriers.
__global__ __launch_bounds__(256,3) void edge_round_mfma(
  unsigned* __restrict__ eg,           // [B][N(j)][N(i)][64] bf16-pairs
  const unsigned* __restrict__ wT,     // [Wl_e|Wm_e|Wu_e|Wu_m] each [c][64] bf16-pairs
  const int* __restrict__ ids,         // [B][N][N]
  int first,
  const float* __restrict__ embZ, const float* __restrict__ embM,
  const float* __restrict__ embU,      // [4][128] f32 tables (emb @ W)
  const float* __restrict__ a_l, const float* __restrict__ b_l,
  const float* __restrict__ a_m, const float* __restrict__ b_m,
  const float* __restrict__ bl1, const float* __restrict__ wl2,
  const float* __restrict__ bl2, const float* __restrict__ bm,
  const float* __restrict__ bu,
  const int* __restrict__ event_nums,
  float* __restrict__ ms)              // [B][N][128], pre-zeroed, accumulated atomically
{
  __shared__ unsigned e_s[64*68];    // E rows bf16 k-pairs, padded
  __shared__ unsigned m_a[64*68];    // m (later u), padded
  __shared__ float adj[64];
  __shared__ float bL_s[128], bM_s[128], bu_s[128], wl2_s[128];
  __shared__ float tabZ[512], tabM[512], tabU[512];
  __shared__ int id_s[64];
  unsigned short* m16 = (unsigned short*)m_a;

  const int t = threadIdx.x;
  const int b = blockIdx.x >> 8, j = (blockIdx.x >> 1) & 127, half = blockIdx.x & 1;
  const int vn = event_nums[b];
  const int row0 = half*64;
  int vnl = vn - row0; vnl = vnl < 0 ? 0 : (vnl > 64 ? 64 : vnl);

  if (j >= vn || vnl == 0) return;

  unsigned* eblk = eg + (size_t)(b*128 + j) * 8192;
  const bool fst = (first != 0);
  const float bl2v = bl2[0];

  if (t < 128) {
    bL_s[t] = b_l[(size_t)(b*128 + j)*128 + t] + bl1[t];
    bM_s[t] = b_m[(size_t)(b*128 + j)*128 + t] + bm[t];
    bu_s[t] = bu[t];
    wl2_s[t] = wl2[t];
  }
  if (t < 64) {
    adj[t] = 0.f;
    if (fst) id_s[t] = ids[((size_t)(b*128 + row0 + t))*128 + j];
  }
  if (fst) {
    for (int i = t; i < 512; i += 256) {
      tabZ[i] = embZ[i]; tabM[i] = embM[i]; tabU[i] = embU[i];
    }
  } else {
    const int vnc16 = (vnl + 15) & ~15;
    const int srow = t >> 4, c4 = (t & 15) * 4;
    #pragma unroll
    for (int it = 0; it < 4; ++it) {
      int lr = it*16 + srow;
      if (lr < vnc16)
        *(uint4*)&e_s[lr*68 + c4] = *(const uint4*)&eblk[(size_t)(row0 + lr)*64 + c4];
    }
  }
  __syncthreads();   // B1

  const int lane = t & 63, wv = t >> 6;
  const int q = lane >> 4, n = lane & 15;
  const int rh2 = wv >> 1, ch = wv & 1;

  int nvt = (vnl - rh2*32 + 15) >> 4;
  nvt = nvt < 0 ? 0 : (nvt > 2 ? 2 : nvt);

  const unsigned* wz  = wT;
  const unsigned* wm  = wT + 8192;
  const unsigned* wue = wT + 16384;
  const unsigned* wum = wT + 24576;

  int colg[4];
  #pragma unroll
  for (int ct = 0; ct < 4; ++ct) colg[ct] = ch*64 + ct*16 + n;

  int arowi[2];
  #pragma unroll
  for (int rt = 0; rt < 2; ++rt) arowi[rt] = rh2*32 + rt*16 + n;

  // ---------- prefetch Z-epilogue operands (32 independent scalar loads) ----------
  float alv[2][4][4];
  #pragma unroll
  for (int rt = 0; rt < 2; ++rt)
    #pragma unroll
    for (int ct = 0; ct < 4; ++ct)
      #pragma unroll
      for (int r = 0; r < 4; ++r) {
        int lrow = rh2*32 + rt*16 + q*4 + r;
        alv[rt][ct][r] = a_l[(size_t)(b*128 + row0 + lrow)*128 + colg[ct]];
      }

  // ---------- PASS Z ----------
  floatx4 az[2][4];
  #pragma unroll
  for (int rt = 0; rt < 2; ++rt)
    #pragma unroll
    for (int ct = 0; ct < 4; ++ct) az[rt][ct] = (floatx4){0.f,0.f,0.f,0.f};
  if (!fst) {
    uint4 bb[4][4];   // hoisted: 16 independent loads in flight
    #pragma unroll
    for (int kb = 0; kb < 4; ++kb)
      #pragma unroll
      for (int ct = 0; ct < 4; ++ct)
        bb[kb][ct] = *(const uint4*)(wz + colg[ct]*64 + kb*16 + q*4);
    #pragma unroll
    for (int kb = 0; kb < 4; ++kb)
      #pragma unroll
      for (int rt = 0; rt < 2; ++rt)
        if (rt < nvt) {
          uint4 a = *(const uint4*)&e_s[arowi[rt]*68 + kb*16 + q*4];
          #pragma unroll
          for (int ct = 0; ct < 4; ++ct)
            az[rt][ct] = __builtin_amdgcn_mfma_f32_16x16x32_bf16(as_s8(a), as_s8(bb[kb][ct]), az[rt][ct], 0, 0, 0);
        }
  }

  // Z epilogue: adj[row] += sum_col relu(z + a_l + bL) * wl2
  {
    float wl2v[4], bLv[4];
    #pragma unroll
    for (int ct = 0; ct < 4; ++ct) { wl2v[ct] = wl2_s[colg[ct]]; bLv[ct] = bL_s[colg[ct]]; }
    #pragma unroll
    for (int rt = 0; rt < 2; ++rt) {
      if (rt < nvt) {
        float szr[4] = {0.f,0.f,0.f,0.f};
        #pragma unroll
        for (int ct = 0; ct < 4; ++ct) {
          #pragma unroll
          for (int r = 0; r < 4; ++r) {
            int lrow = rh2*32 + rt*16 + q*4 + r;
            float zraw = fst ? tabZ[id_s[lrow]*128 + colg[ct]] : az[rt][ct][r];
            float zv = fmaxf(zraw + alv[rt][ct][r] + bLv[ct], 0.f);
            szr[r] += zv * wl2v[ct];
          }
        }
        #pragma unroll
        for (int r = 0; r < 4; ++r) {
          szr[r] += __shfl_xor(szr[r], 1);
          szr[r] += __shfl_xor(szr[r], 2);
          szr[r] += __shfl_xor(szr[r], 4);
          szr[r] += __shfl_xor(szr[r], 8);
        }
        if (n == 0) {
          #pragma unroll
          for (int r = 0; r < 4; ++r)
            atomicAdd(&adj[rh2*32 + rt*16 + q*4 + r], szr[r]);
        }
      }
    }
  }

  // ---------- prefetch M-epilogue operands + PASS M MFMA (before adj barrier) ----------
  float amv[2][4][4];
  #pragma unroll
  for (int rt = 0; rt < 2; ++rt)
    #pragma unroll
    for (int ct = 0; ct < 4; ++ct)
      #pragma unroll
      for (int r = 0; r < 4; ++r) {
        int lrow = rh2*32 + rt*16 + q*4 + r;
        amv[rt][ct][r] = a_m[(size_t)(b*128 + row0 + lrow)*128 + colg[ct]];
      }

  floatx4 am[2][4];
  #pragma unroll
  for (int rt = 0; rt < 2; ++rt)
    #pragma unroll
    for (int ct = 0; ct < 4; ++ct) am[rt][ct] = (floatx4){0.f,0.f,0.f,0.f};
  if (!fst) {
    uint4 bb[4][4];
    #pragma unroll
    for (int kb = 0; kb < 4; ++kb)
      #pragma unroll
      for (int ct = 0; ct < 4; ++ct)
        bb[kb][ct] = *(const uint4*)(wm + colg[ct]*64 + kb*16 + q*4);
    #pragma unroll
    for (int kb = 0; kb < 4; ++kb)
      #pragma unroll
      for (int rt = 0; rt < 2; ++rt)
        if (rt < nvt) {
          uint4 a = *(const uint4*)&e_s[arowi[rt]*68 + kb*16 + q*4];
          #pragma unroll
          for (int ct = 0; ct < 4; ++ct)
            am[rt][ct] = __builtin_amdgcn_mfma_f32_16x16x32_bf16(as_s8(a), as_s8(bb[kb][ct]), am[rt][ct], 0, 0, 0);
        }
  }
  __syncthreads();   // B2: adj complete

  // M epilogue (inline sigmoid of adj) -> m16 bf16; direct global ms atomics
  {
    float bMv[4];
    #pragma unroll
    for (int ct = 0; ct < 4; ++ct) bMv[ct] = bM_s[colg[ct]];
    float colsum[4] = {0.f,0.f,0.f,0.f};
    #pragma unroll
    for (int rt = 0; rt < 2; ++rt) {
      if (rt < nvt) {
        #pragma unroll
        for (int ct = 0; ct < 4; ++ct) {
          #pragma unroll
          for (int r = 0; r < 4; ++r) {
            int lrow = rh2*32 + rt*16 + q*4 + r;
            float mraw = fst ? tabM[id_s[lrow]*128 + colg[ct]] : am[rt][ct][r];
            float mv = fmaxf(mraw + amv[rt][ct][r] + bMv[ct], 0.f);
            float sc = (lrow < vnl) ? sigf(adj[lrow] + bl2v) : 0.f;
            mv *= sc;
            m16[lrow*136 + colg[ct]] = bf16_1(mv);
            colsum[ct] += mv;
          }
        }
      }
    }
    #pragma unroll
    for (int ct = 0; ct < 4; ++ct) {
      float v = colsum[ct];
      v += __shfl_xor(v, 16);
      v += __shfl_xor(v, 32);
      if (lane < 16) atomicAdd(&ms[(size_t)(b*128 + j)*128 + colg[ct]], v);
    }
  }
  __syncthreads();   // B3: m16 ready

  // ---------- PASS U: U = E@Wu_e + M@Wu_m ----------
  floatx4 au[2][4];
  if (fst) {
    #pragma unroll
    for (int rt = 0; rt < 2; ++rt)
      #pragma unroll
      for (int ct = 0; ct < 4; ++ct) {
        au[rt][ct] = (floatx4){0.f,0.f,0.f,0.f};
        if (rt < nvt)
          #pragma unroll
          for (int r = 0; r < 4; ++r) {
            int lrow = rh2*32 + rt*16 + q*4 + r;
            au[rt][ct][r] = tabU[id_s[lrow]*128 + colg[ct]];
          }
      }
  } else {
    #pragma unroll
    for (int rt = 0; rt < 2; ++rt)
      #pragma unroll
      for (int ct = 0; ct < 4; ++ct) au[rt][ct] = (floatx4){0.f,0.f,0.f,0.f};
    uint4 bb[4][4];
    #pragma unroll
    for (int kb = 0; kb < 4; ++kb)
      #pragma unroll
      for (int ct = 0; ct < 4; ++ct)
        bb[kb][ct] = *(const uint4*)(wue + colg[ct]*64 + kb*16 + q*4);
    #pragma unroll
    for (int kb = 0; kb < 4; ++kb)
      #pragma unroll
      for (int rt = 0; rt < 2; ++rt)
        if (rt < nvt) {
          uint4 a = *(const uint4*)&e_s[arowi[rt]*68 + kb*16 + q*4];
          #pragma unroll
          for (int ct = 0; ct < 4; ++ct)
            au[rt][ct] = __builtin_amdgcn_mfma_f32_16x16x32_bf16(as_s8(a), as_s8(bb[kb][ct]), au[rt][ct], 0, 0, 0);
        }
  }
  {
    uint4 bb[4][4];
    #pragma unroll
    for (int kb = 0; kb < 4; ++kb)
      #pragma unroll
      for (int ct = 0; ct < 4; ++ct)
        bb[kb][ct] = *(const uint4*)(wum + colg[ct]*64 + kb*16 + q*4);
    #pragma unroll
    for (int kb = 0; kb < 4; ++kb)
      #pragma unroll
      for (int rt = 0; rt < 2; ++rt)
        if (rt < nvt) {
          uint4 a = *(const uint4*)&m_a[arowi[rt]*68 + kb*16 + q*4];
          #pragma unroll
          for (int ct = 0; ct < 4; ++ct)
            au[rt][ct] = __builtin_amdgcn_mfma_f32_16x16x32_bf16(as_s8(a), as_s8(bb[kb][ct]), au[rt][ct], 0, 0, 0);
        }
  }
  __syncthreads();   // B4: all m_a reads done before overwrite

  {
    float buv[4];
    #pragma unroll
    for (int ct = 0; ct < 4; ++ct) buv[ct] = bu_s[colg[ct]];
    #pragma unroll
    for (int rt = 0; rt < 2; ++rt) {
      if (rt < nvt) {
        #pragma unroll
        for (int ct = 0; ct < 4; ++ct)
          #pragma unroll
          for (int r = 0; r < 4; ++r) {
            int lrow = rh2*32 + rt*16 + q*4 + r;
            m16[lrow*136 + colg[ct]] = bf16_1(fmaxf(au[rt][ct][r] + buv[ct], 0.f));
          }
      }
    }
  }
  __syncthreads();   // B5
  #pragma unroll
  for (int it = 0; it < 16; ++it) {
    int f = it*256 + t;
    int lr = f >> 6, c2 = f & 63;
    if (row0 + lr < vn) eblk[(size_t)(row0 + lr)*64 + c2] = m_a[lr*68 + c2];
  }
}

// ---------- MFMA readout, both GEMMs on matrix cores ----------
__global__ __launch_bounds__(256,4) void readout_mfma(
  const unsigned* __restrict__ eg,
  const unsigned* __restrict__ wr1T,   // [256 cols][128 k2] bf16-pairs
  const unsigned* __restrict__ wr2T,   // [16 cols][128 k2] bf16-pairs (cols 10..15 zero)
  const float* __restrict__ br1, const float* __restrict__ br2,
  const int* __restrict__ event_nums, float* __restrict__ out)
{
  __shared__ unsigned f_s[64*132];     // feat bf16 pairs, padded rows; reused as h16
  __shared__ int iu_s[64], ju_s[64];
  unsigned short* h16 = (unsigned short*)f_s;   // overlay: 64 rows x 264 halves

  const int t = threadIdx.x;
  const int b = blockIdx.x / 127, pb = blockIdx.x % 127;
  const int vn = event_nums[b];

  if (t < 64) {
    int p = pb*64 + t;
    float disc = (float)((2*NN-1)*(2*NN-1) - 8*p);
    int iu = (int)(((float)(2*NN-1) - sqrtf(disc)) * 0.5f);
    if (iu < 0) iu = 0; if (iu > NN-2) iu = NN-2;
    while (iu < NN-2 && ((iu+1)*(2*NN-2-iu))/2 <= p) ++iu;
    while (iu > 0 && (iu*(2*NN-1-iu))/2 > p) --iu;
    int ju = p - (iu*(2*NN-1-iu))/2 + iu + 1;
    iu_s[t] = iu; ju_s[t] = ju;
  }
  __syncthreads();

  #pragma unroll
  for (int it = 0; it < 32; ++it) {
    int f = it*256 + t;
    int pr = f >> 7, w = f & 127;
    int side = w >> 6, k2l = w & 63;
    int iu = iu_s[pr], ju = ju_s[pr];
    size_t base = side ? (((size_t)(b*128 + iu))*128 + ju)*64
                       : (((size_t)(b*128 + ju))*128 + iu)*64;
    f_s[pr*132 + w] = eg[base + k2l];
  }
  __syncthreads();

  const int lane = t & 63, wv = t >> 6;
  const int q = lane >> 4, n = lane & 15;
  int colg[4];
  #pragma unroll
  for (int ct = 0; ct < 4; ++ct) colg[ct] = wv*64 + ct*16 + n;

  floatx4 acc[4][4];
  #pragma unroll
  for (int rt = 0; rt < 4; ++rt)
    #pragma unroll
    for (int ct = 0; ct < 4; ++ct) acc[rt][ct] = (floatx4){0.f,0.f,0.f,0.f};

  #pragma unroll
  for (int kb = 0; kb < 8; ++kb) {
    uint4 bb[4];
    #pragma unroll
    for (int ct = 0; ct < 4; ++ct) bb[ct] = *(const uint4*)(wr1T + (size_t)colg[ct]*128 + kb*16 + q*4);
    #pragma unroll
    for (int rt = 0; rt < 4; ++rt) {
      uint4 a = *(const uint4*)&f_s[(rt*16 + n)*132 + kb*16 + q*4];
      #pragma unroll
      for (int ct = 0; ct < 4; ++ct)
        acc[rt][ct] = __builtin_amdgcn_mfma_f32_16x16x32_bf16(as_s8(a), as_s8(bb[ct]), acc[rt][ct], 0, 0, 0);
    }
  }
  __syncthreads();

  {
    float brv[4];
    #pragma unroll
    for (int ct = 0; ct < 4; ++ct) brv[ct] = br1[colg[ct]];
    #pragma unroll
    for (int rt = 0; rt < 4; ++rt)
      #pragma unroll
      for (int ct = 0; ct < 4; ++ct)
        #pragma unroll
        for (int r = 0; r < 4; ++r) {
          int pr = rt*16 + q*4 + r;
          h16[pr*264 + colg[ct]] = bf16_1(fmaxf(acc[rt][ct][r] + brv[ct], 0.f));
        }
  }
  __syncthreads();

  floatx4 acc2 = (floatx4){0.f,0.f,0.f,0.f};
  #pragma unroll
  for (int kb = 0; kb < 8; ++kb) {
    uint4 bb = *(const uint4*)(wr2T + n*128 + kb*16 + q*4);
    uint4 a  = *(const uint4*)&f_s[(wv*16 + n)*132 + kb*16 + q*4];
    acc2 = __builtin_amdgcn_mfma_f32_16x16x32_bf16(as_s8(a), as_s8(bb), acc2, 0, 0, 0);
  }

  if (n < 10) {
    float bias = br2[n];
    #pragma unroll
    for (int r = 0; r < 4; ++r) {
      int pr = wv*16 + q*4 + r;
      int iu = iu_s[pr], ju = ju_s[pr];
      if (ju < vn) {
        int idx = iu*vn - (iu*(iu+1))/2 + (ju - iu - 1);
        out[(((size_t)b*5 + (n>>1))*PP + idx)*2 + (n&1)] = acc2[r] + bias;
      }
    }
  }
}

extern "C" void kernel_launch(void* const* d_in, const int* in_sizes, int n_in,
                              void* d_out, int out_size, void* d_ws, size_t ws_size,
                              hipStream_t stream) {
  const int*   edge_ids      = (const int*)d_in[0];
  const float* node_features = (const float*)d_in[1];
  const int*   event_nums    = (const int*)d_in[3];
  const float* emb  = (const float*)d_in[4];
  const float* Wl_e = (const float*)d_in[5];
  const float* Wl_w = (const float*)d_in[6];
  const float* Wl_v = (const float*)d_in[7];
  const float* bl1  = (const float*)d_in[8];
  const float* wl2  = (const float*)d_in[9];
  const float* bl2  = (const float*)d_in[10];
  const float* Wm_w = (const float*)d_in[11];
  const float* Wm_v = (const float*)d_in[12];
  const float* Wm_e = (const float*)d_in[13];
  const float* bm   = (const float*)d_in[14];
  const float* Wu_e = (const float*)d_in[15];
  const float* Wu_m = (const float*)d_in[16];
  const float* bu   = (const float*)d_in[17];
  const float* W_ih = (const float*)d_in[18];
  const float* W_hh = (const float*)d_in[19];
  const float* b_ih = (const float*)d_in[20];
  const float* b_hh = (const float*)d_in[21];
  const float* Wr1  = (const float*)d_in[22];
  const float* br1  = (const float*)d_in[23];
  const float* Wr2  = (const float*)d_in[24];
  const float* br2  = (const float*)d_in[25];

  const size_t SZ_E = (size_t)134217728;       // B*N*N*64 u32
  const size_t SZ_S = (size_t)2097152;         // B*N*128 f32
  const size_t SZ_W = (size_t)131072;          // 32768 u32
  const size_t SZ_W2 = (size_t)8192;           // 2048 u32
  const size_t SZ_TAB = (size_t)2048;          // 512 f32 each
  const size_t need = SZ_E + 6*SZ_S + 2*SZ_W + SZ_W2 + 3*SZ_TAB;

  hipMemsetAsync(d_out, 0, (size_t)out_size * sizeof(float), stream);
  if (ws_size < need) return;   // clean failure instead of OOB fault

  char* w = (char*)d_ws;
  unsigned* eg   = (unsigned*)w; w += SZ_E;
  float* h_ws = (float*)w; w += SZ_S;
  float* a_l  = (float*)w; w += SZ_S;
  float* b_l  = (float*)w; w += SZ_S;
  float* a_m  = (float*)w; w += SZ_S;
  float* b_m  = (float*)w; w += SZ_S;
  float* ms   = (float*)w; w += SZ_S;
  unsigned* wT   = (unsigned*)w; w += SZ_W;
  unsigned* wr1T = (unsigned*)w; w += SZ_W;
  unsigned* wr2T = (unsigned*)w; w += SZ_W2;
  float* embZ = (float*)w; w += SZ_TAB;
  float* embM = (float*)w; w += SZ_TAB;
  float* embU = (float*)w; w += SZ_TAB;

  hipLaunchKernelGGL(conv_w_kernel, dim3(256), dim3(256), 0, stream,
      Wl_e, Wm_e, Wu_e, Wu_m, Wr1, Wr2, emb, wT, wr1T, wr2T, embZ, embM, embU);

  hipLaunchKernelGGL(gru_proj_kernel, dim3(1024), dim3(256), 0, stream,
      0, ms, node_features, h_ws, W_ih, W_hh, b_ih, b_hh,
      Wl_w, Wl_v, Wm_w, Wm_v, event_nums, a_l, b_l, a_m, b_m);

  for (int r = 0; r < 3; ++r) {
    hipMemsetAsync(ms, 0, SZ_S, stream);   // ms accumulated atomically by edge kernel
    hipLaunchKernelGGL(edge_round_mfma, dim3(8192), dim3(256), 0, stream,
        eg, wT, edge_ids, (r == 0) ? 1 : 0, embZ, embM, embU,
        a_l, b_l, a_m, b_m, bl1, wl2, bl2, bm, bu, event_nums, ms);
    if (r < 2) {
      const float* hin = (r == 0) ? node_features : h_ws;
      hipLaunchKernelGGL(gru_proj_kernel, dim3(1024), dim3(256), 0, stream,
          1, ms, hin, h_ws, W_ih, W_hh, b_ih, b_hh,
          Wl_w, Wl_v, Wm_w, Wm_v, event_nums, a_l, b_l, a_m, b_m);
    }
  }

  hipLaunchKernelGGL(readout_mfma, dim3(BB*127), dim3(256), 0, stream,
      eg, wr1T, wr2T, br1, br2, event_nums, (float*)d_out);
}

// Round 12
// 789.107 us; speedup vs baseline: 1.1277x; 1.0371x over previous
//
#include <hip/hip_runtime.h>
#include <cstddef>

// Problem constants
#define BB 32
#define NN 128
#define PP 8128

typedef __attribute__((ext_vector_type(8))) short short8;
typedef __attribute__((ext_vector_type(4))) float floatx4;

union U4S8 { uint4 u; short8 s; };
__device__ __forceinline__ short8 as_s8(uint4 v){ U4S8 x; x.u = v; return x.s; }

// ---------- bf16 helpers ----------
__device__ __forceinline__ float bf_lo(unsigned u){ union{unsigned v;float f;}x; x.v=u<<16; return x.f; }
__device__ __forceinline__ float bf_hi(unsigned u){ union{unsigned v;float f;}x; x.v=u&0xffff0000u; return x.f; }
__device__ __forceinline__ unsigned pack_bf16(float a, float b){
  union{float f;unsigned u;}xa,xb; xa.f=a; xb.f=b;
  unsigned ua=xa.u, ub=xb.u;
  ua = (ua + 0x7fffu + ((ua>>16)&1u)) >> 16;
  ub = (ub + 0x7fffu + ((ub>>16)&1u)) >> 16;
  return (ua & 0xffffu) | (ub << 16);
}
__device__ __forceinline__ unsigned short bf16_1(float a){
  union{float f;unsigned u;}x; x.f=a;
  return (unsigned short)((x.u + 0x7fffu + ((x.u>>16)&1u)) >> 16);
}
__device__ __forceinline__ float sigf(float x){ return 1.f/(1.f + __expf(-x)); }

// ---------- weight conversion + round-0 tables ----------
__global__ __launch_bounds__(256,4) void conv_w_kernel(
  const float* __restrict__ Wl_e, const float* __restrict__ Wm_e,
  const float* __restrict__ Wu_e, const float* __restrict__ Wu_m,
  const float* __restrict__ Wr1, const float* __restrict__ Wr2,
  const float* __restrict__ emb,
  unsigned* __restrict__ wT, unsigned* __restrict__ wr1T,
  unsigned* __restrict__ wr2T,
  float* __restrict__ embZ, float* __restrict__ embM, float* __restrict__ embU)
{
  int tid = blockIdx.x*256 + threadIdx.x;   // 65536 total
  if (tid < 2048) {   // Wr2 [256][10] -> B-frag layout [16 cols][128 k2], zero-padded
    int c = tid >> 7, k2 = tid & 127;
    unsigned v = 0;
    if (c < 10) v = pack_bf16(Wr2[(2*k2)*10 + c], Wr2[(2*k2+1)*10 + c]);
    wr2T[c*128 + k2] = v;
  }
  if (tid >= 4096 && tid < 5632) {   // round-0 tables: emb(4x128) @ W(128x128), f32
    int idx = tid - 4096;            // 0..1535
    int tb = idx >> 9;               // 0..2
    int r  = idx & 511;
    int id = r >> 7, c = r & 127;
    const float* W = (tb==0) ? Wl_e : (tb==1) ? Wm_e : Wu_e;
    float s = 0.f;
    #pragma unroll 4
    for (int k = 0; k < 128; ++k) s += emb[id*128 + k] * W[(size_t)k*128 + c];
    float* T = (tb==0) ? embZ : (tb==1) ? embM : embU;
    T[r] = s;
  }
  if (tid < 32768) {
    int mat = tid >> 13, r = tid & 8191;
    int k2 = r >> 7, c = r & 127;
    const float* W = (mat==0) ? Wl_e : (mat==1) ? Wm_e : (mat==2) ? Wu_e : Wu_m;
    wT[mat*8192 + c*64 + k2] = pack_bf16(W[(2*k2)*128 + c], W[(2*k2+1)*128 + c]);
  } else {
    int r = tid - 32768;
    int k2 = r >> 8, c = r & 255;
    wr1T[(size_t)c*128 + k2] = pack_bf16(Wr1[(2*k2)*256 + c], Wr1[(2*k2+1)*256 + c]);
  }
}

// ---------- fused GRU + node projections ----------
__global__ __launch_bounds__(256,4) void gru_proj_kernel(
  int do_gru,
  const float* __restrict__ ms, const float* __restrict__ h_in, float* __restrict__ h_out,
  const float* __restrict__ W_ih, const float* __restrict__ W_hh,
  const float* __restrict__ b_ih, const float* __restrict__ b_hh,
  const float* __restrict__ Wl_w, const float* __restrict__ Wl_v,
  const float* __restrict__ Wm_w, const float* __restrict__ Wm_v,
  const int* __restrict__ event_nums,
  float* __restrict__ a_l, float* __restrict__ b_l,
  float* __restrict__ a_m, float* __restrict__ b_m)
{
  __shared__ float h_s[4][128];
  __shared__ float ms_s[4][128];
  const int t = threadIdx.x, blk = blockIdx.x;
  const int b = blk >> 5, n0 = (blk & 31) * 4;
  const int vn = event_nums[b];
  const int g = t >> 6, l = t & 63;
  const int row = b*128 + n0 + g;

  h_s[g][l]    = h_in[(size_t)row*128 + l];
  h_s[g][l+64] = h_in[(size_t)row*128 + l + 64];
  if (do_gru) {
    ms_s[g][l]    = ms[(size_t)row*128 + l];
    ms_s[g][l+64] = ms[(size_t)row*128 + l + 64];
  }
  __syncthreads();

  if (do_gru) {
    float acc[12] = {};
    #pragma unroll 4
    for (int k = 0; k < 128; ++k) {
      float mv = ms_s[g][k], hv = h_s[g][k];
      #pragma unroll
      for (int u = 0; u < 6; ++u) {
        acc[u]   += mv * W_ih[(size_t)k*384 + l + 64*u];
        acc[6+u] += hv * W_hh[(size_t)k*384 + l + 64*u];
      }
    }
    const bool valid = (n0 + g) < vn;
    float hnew[2];
    #pragma unroll
    for (int u = 0; u < 2; ++u) {
      int c = l + 64*u;
      float ir = acc[u]     + b_ih[c];
      float iz = acc[u+2]   + b_ih[128+c];
      float in_= acc[u+4]   + b_ih[256+c];
      float hr = acc[6+u]   + b_hh[c];
      float hz = acc[8+u]   + b_hh[128+c];
      float hn = acc[10+u]  + b_hh[256+c];
      float r  = sigf(ir + hr);
      float zg = sigf(iz + hz);
      float nn = tanhf(in_ + r*hn);
      float hold = h_s[g][c];
      hnew[u] = valid ? (1.f - zg)*nn + zg*hold : hold;
    }
    __syncthreads();
    #pragma unroll
    for (int u = 0; u < 2; ++u) {
      int c = l + 64*u;
      h_s[g][c] = hnew[u];
      h_out[(size_t)row*128 + c] = hnew[u];
    }
    __syncthreads();
  }

  {
    const float* Wp[4] = {Wl_w, Wl_v, Wm_w, Wm_v};
    float* Op[4] = {a_l, b_l, a_m, b_m};
    float acc2[8] = {};
    #pragma unroll 4
    for (int k = 0; k < 128; ++k) {
      float hv = h_s[g][k];
      #pragma unroll
      for (int u = 0; u < 8; ++u)
        acc2[u] += hv * Wp[u>>1][(size_t)k*128 + l + 64*(u&1)];
    }
    #pragma unroll
    for (int u = 0; u < 8; ++u)
      Op[u>>1][(size_t)row*128 + l + 64*(u&1)] = acc2[u];
  }
}

// ---------- edge round 0: table-driven (no E GEMMs), only M@Wu_m on MFMA ----------
// grid = B*N*2, block 256. LDS ~27 KB -> 6 blocks/CU.
__global__ __launch_bounds__(256,4) void edge_round_first(
  unsigned* __restrict__ eg,
  const unsigned* __restrict__ wT,     // need wum = wT+24576
  const int* __restrict__ ids,
  const float* __restrict__ embZ, const float* __restrict__ embM,
  const float* __restrict__ embU,
  const float* __restrict__ a_l, const float* __restrict__ b_l,
  const float* __restrict__ a_m, const float* __restrict__ b_m,
  const float* __restrict__ bl1, const float* __restrict__ wl2,
  const float* __restrict__ bl2, const float* __restrict__ bm,
  const float* __restrict__ bu,
  const int* __restrict__ event_nums,
  float* __restrict__ ms)
{
  __shared__ unsigned m_a[64*68];
  __shared__ float adj[64], svec[64], msum[128];
  __shared__ float bL_s[128], bM_s[128], bu_s[128], wl2_s[128];
  __shared__ float tabZ[512], tabM[512], tabU[512];
  __shared__ int id_s[64];
  unsigned short* m16 = (unsigned short*)m_a;

  const int t = threadIdx.x;
  const int b = blockIdx.x >> 8, j = (blockIdx.x >> 1) & 127, half = blockIdx.x & 1;
  const int vn = event_nums[b];
  const int row0 = half*64;
  int vnl = vn - row0; vnl = vnl < 0 ? 0 : (vnl > 64 ? 64 : vnl);
  if (j >= vn || vnl == 0) return;

  unsigned* eblk = eg + (size_t)(b*128 + j) * 8192;

  if (t < 128) {
    bL_s[t] = b_l[(size_t)(b*128 + j)*128 + t] + bl1[t];
    bM_s[t] = b_m[(size_t)(b*128 + j)*128 + t] + bm[t];
    bu_s[t] = bu[t];
    wl2_s[t] = wl2[t];
    msum[t] = 0.f;
  }
  if (t < 64) {
    adj[t] = 0.f;
    id_s[t] = ids[((size_t)(b*128 + row0 + t))*128 + j];
  }
  for (int i = t; i < 512; i += 256) {
    tabZ[i] = embZ[i]; tabM[i] = embM[i]; tabU[i] = embU[i];
  }
  __syncthreads();   // B1

  const int lane = t & 63, wv = t >> 6;
  const int q = lane >> 4, n = lane & 15;
  const int rh2 = wv >> 1, ch = wv & 1;

  int nvt = (vnl - rh2*32 + 15) >> 4;
  nvt = nvt < 0 ? 0 : (nvt > 2 ? 2 : nvt);

  const unsigned* wum = wT + 24576;
  int colg[4];
  #pragma unroll
  for (int ct = 0; ct < 4; ++ct) colg[ct] = ch*64 + ct*16 + n;
  int arowi[2];
  #pragma unroll
  for (int rt = 0; rt < 2; ++rt) arowi[rt] = rh2*32 + rt*16 + n;

  // Z epilogue from tables
  {
    float wl2v[4], bLv[4];
    #pragma unroll
    for (int ct = 0; ct < 4; ++ct) { wl2v[ct] = wl2_s[colg[ct]]; bLv[ct] = bL_s[colg[ct]]; }
    #pragma unroll
    for (int rt = 0; rt < 2; ++rt) {
      if (rt < nvt) {
        float szr[4] = {0.f,0.f,0.f,0.f};
        #pragma unroll
        for (int ct = 0; ct < 4; ++ct) {
          #pragma unroll
          for (int r = 0; r < 4; ++r) {
            int lrow = rh2*32 + rt*16 + q*4 + r;
            float al = a_l[(size_t)(b*128 + row0 + lrow)*128 + colg[ct]];
            float zv = fmaxf(tabZ[id_s[lrow]*128 + colg[ct]] + al + bLv[ct], 0.f);
            szr[r] += zv * wl2v[ct];
          }
        }
        #pragma unroll
        for (int r = 0; r < 4; ++r) {
          szr[r] += __shfl_xor(szr[r], 1);
          szr[r] += __shfl_xor(szr[r], 2);
          szr[r] += __shfl_xor(szr[r], 4);
          szr[r] += __shfl_xor(szr[r], 8);
        }
        if (n == 0) {
          #pragma unroll
          for (int r = 0; r < 4; ++r)
            atomicAdd(&adj[rh2*32 + rt*16 + q*4 + r], szr[r]);
        }
      }
    }
  }
  __syncthreads();   // B2
  if (t < 64) svec[t] = sigf(adj[t] + bl2[0]);
  __syncthreads();   // B2'

  // M epilogue from tables -> m16, msum
  {
    float bMv[4];
    #pragma unroll
    for (int ct = 0; ct < 4; ++ct) bMv[ct] = bM_s[colg[ct]];
    float colsum[4] = {0.f,0.f,0.f,0.f};
    #pragma unroll
    for (int rt = 0; rt < 2; ++rt) {
      if (rt < nvt) {
        #pragma unroll
        for (int ct = 0; ct < 4; ++ct) {
          #pragma unroll
          for (int r = 0; r < 4; ++r) {
            int lrow = rh2*32 + rt*16 + q*4 + r;
            float am = a_m[(size_t)(b*128 + row0 + lrow)*128 + colg[ct]];
            float mv = fmaxf(tabM[id_s[lrow]*128 + colg[ct]] + am + bMv[ct], 0.f);
            float sc = (lrow < vnl) ? svec[lrow] : 0.f;
            mv *= sc;
            m16[lrow*136 + colg[ct]] = bf16_1(mv);
            colsum[ct] += mv;
          }
        }
      }
    }
    #pragma unroll
    for (int ct = 0; ct < 4; ++ct) {
      float v = colsum[ct];
      v += __shfl_xor(v, 16);
      v += __shfl_xor(v, 32);
      if (lane < 16) atomicAdd(&msum[colg[ct]], v);
    }
  }
  __syncthreads();   // B3
  if (t < 128) atomicAdd(&ms[(size_t)(b*128 + j)*128 + t], msum[t]);

  // U = tabU gather + M@Wu_m
  floatx4 au[2][4];
  #pragma unroll
  for (int rt = 0; rt < 2; ++rt)
    #pragma unroll
    for (int ct = 0; ct < 4; ++ct) {
      au[rt][ct] = (floatx4){0.f,0.f,0.f,0.f};
      if (rt < nvt)
        #pragma unroll
        for (int r = 0; r < 4; ++r) {
          int lrow = rh2*32 + rt*16 + q*4 + r;
          au[rt][ct][r] = tabU[id_s[lrow]*128 + colg[ct]];
        }
    }
  #pragma unroll
  for (int kb = 0; kb < 4; ++kb) {
    uint4 bb[4];
    #pragma unroll
    for (int ct = 0; ct < 4; ++ct) bb[ct] = *(const uint4*)(wum + colg[ct]*64 + kb*16 + q*4);
    #pragma unroll
    for (int rt = 0; rt < 2; ++rt)
      if (rt < nvt) {
        uint4 a = *(const uint4*)&m_a[arowi[rt]*68 + kb*16 + q*4];
        #pragma unroll
        for (int ct = 0; ct < 4; ++ct)
          au[rt][ct] = __builtin_amdgcn_mfma_f32_16x16x32_bf16(as_s8(a), as_s8(bb[ct]), au[rt][ct], 0, 0, 0);
      }
  }
  __syncthreads();   // B4

  {
    float buv[4];
    #pragma unroll
    for (int ct = 0; ct < 4; ++ct) buv[ct] = bu_s[colg[ct]];
    #pragma unroll
    for (int rt = 0; rt < 2; ++rt)
      if (rt < nvt)
        #pragma unroll
        for (int ct = 0; ct < 4; ++ct)
          #pragma unroll
          for (int r = 0; r < 4; ++r) {
            int lrow = rh2*32 + rt*16 + q*4 + r;
            m16[lrow*136 + colg[ct]] = bf16_1(fmaxf(au[rt][ct][r] + buv[ct], 0.f));
          }
  }
  __syncthreads();   // B5
  #pragma unroll
  for (int it = 0; it < 16; ++it) {
    int f = it*256 + t;
    int lr = f >> 6, c2 = f & 63;
    if (row0 + lr < vn) eblk[(size_t)(row0 + lr)*64 + c2] = m_a[lr*68 + c2];
  }
}

// ---------- edge rounds >=1: 3 MFMA passes, LDS-staged E, 64-row half-blocks ----------
// LDS 37.9 KB -> 4 blocks/CU under launch_bounds(256,4); bb hoisted 2 kb at a time.
__global__ __launch_bounds__(256,4) void edge_round_rest(
  unsigned* __restrict__ eg,
  const unsigned* __restrict__ wT,
  const float* __restrict__ a_l, const float* __restrict__ b_l,
  const float* __restrict__ a_m, const float* __restrict__ b_m,
  const float* __restrict__ bl1, const float* __restrict__ wl2,
  const float* __restrict__ bl2, const float* __restrict__ bm,
  const float* __restrict__ bu,
  const int* __restrict__ event_nums,
  float* __restrict__ ms)
{
  __shared__ unsigned e_s[64*68];
  __shared__ unsigned m_a[64*68];
  __shared__ float adj[64], svec[64], msum[128];
  __shared__ float bL_s[128], bM_s[128], bu_s[128], wl2_s[128];
  unsigned short* m16 = (unsigned short*)m_a;

  const int t = threadIdx.x;
  const int b = blockIdx.x >> 8, j = (blockIdx.x >> 1) & 127, half = blockIdx.x & 1;
  const int vn = event_nums[b];
  const int row0 = half*64;
  int vnl = vn - row0; vnl = vnl < 0 ? 0 : (vnl > 64 ? 64 : vnl);
  if (j >= vn || vnl == 0) return;

  unsigned* eblk = eg + (size_t)(b*128 + j) * 8192;

  if (t < 128) {
    bL_s[t] = b_l[(size_t)(b*128 + j)*128 + t] + bl1[t];
    bM_s[t] = b_m[(size_t)(b*128 + j)*128 + t] + bm[t];
    bu_s[t] = bu[t];
    wl2_s[t] = wl2[t];
    msum[t] = 0.f;
  }
  if (t < 64) adj[t] = 0.f;
  {
    const int vnc16 = (vnl + 15) & ~15;
    const int srow = t >> 4, c4 = (t & 15) * 4;
    #pragma unroll
    for (int it = 0; it < 4; ++it) {
      int lr = it*16 + srow;
      if (lr < vnc16)
        *(uint4*)&e_s[lr*68 + c4] = *(const uint4*)&eblk[(size_t)(row0 + lr)*64 + c4];
    }
  }
  __syncthreads();   // B1

  const int lane = t & 63, wv = t >> 6;
  const int q = lane >> 4, n = lane & 15;
  const int rh2 = wv >> 1, ch = wv & 1;

  int nvt = (vnl - rh2*32 + 15) >> 4;
  nvt = nvt < 0 ? 0 : (nvt > 2 ? 2 : nvt);

  const unsigned* wz  = wT;
  const unsigned* wm  = wT + 8192;
  const unsigned* wue = wT + 16384;
  const unsigned* wum = wT + 24576;

  int colg[4];
  #pragma unroll
  for (int ct = 0; ct < 4; ++ct) colg[ct] = ch*64 + ct*16 + n;
  int arowi[2];
  #pragma unroll
  for (int rt = 0; rt < 2; ++rt) arowi[rt] = rh2*32 + rt*16 + n;

  // ---------- PASS Z ----------
  floatx4 az[2][4];
  #pragma unroll
  for (int rt = 0; rt < 2; ++rt)
    #pragma unroll
    for (int ct = 0; ct < 4; ++ct) az[rt][ct] = (floatx4){0.f,0.f,0.f,0.f};
  #pragma unroll
  for (int kp = 0; kp < 2; ++kp) {   // two kb per iteration: 8 B-loads in flight
    uint4 bb[2][4];
    #pragma unroll
    for (int k2 = 0; k2 < 2; ++k2)
      #pragma unroll
      for (int ct = 0; ct < 4; ++ct)
        bb[k2][ct] = *(const uint4*)(wz + colg[ct]*64 + (kp*2 + k2)*16 + q*4);
    #pragma unroll
    for (int k2 = 0; k2 < 2; ++k2)
      #pragma unroll
      for (int rt = 0; rt < 2; ++rt)
        if (rt < nvt) {
          uint4 a = *(const uint4*)&e_s[arowi[rt]*68 + (kp*2 + k2)*16 + q*4];
          #pragma unroll
          for (int ct = 0; ct < 4; ++ct)
            az[rt][ct] = __builtin_amdgcn_mfma_f32_16x16x32_bf16(as_s8(a), as_s8(bb[k2][ct]), az[rt][ct], 0, 0, 0);
        }
  }

  // Z epilogue
  {
    float wl2v[4], bLv[4];
    #pragma unroll
    for (int ct = 0; ct < 4; ++ct) { wl2v[ct] = wl2_s[colg[ct]]; bLv[ct] = bL_s[colg[ct]]; }
    #pragma unroll
    for (int rt = 0; rt < 2; ++rt) {
      if (rt < nvt) {
        float szr[4] = {0.f,0.f,0.f,0.f};
        #pragma unroll
        for (int ct = 0; ct < 4; ++ct) {
          #pragma unroll
          for (int r = 0; r < 4; ++r) {
            int lrow = rh2*32 + rt*16 + q*4 + r;
            float al = a_l[(size_t)(b*128 + row0 + lrow)*128 + colg[ct]];
            float zv = fmaxf(az[rt][ct][r] + al + bLv[ct], 0.f);
            szr[r] += zv * wl2v[ct];
          }
        }
        #pragma unroll
        for (int r = 0; r < 4; ++r) {
          szr[r] += __shfl_xor(szr[r], 1);
          szr[r] += __shfl_xor(szr[r], 2);
          szr[r] += __shfl_xor(szr[r], 4);
          szr[r] += __shfl_xor(szr[r], 8);
        }
        if (n == 0) {
          #pragma unroll
          for (int r = 0; r < 4; ++r)
            atomicAdd(&adj[rh2*32 + rt*16 + q*4 + r], szr[r]);
        }
      }
    }
  }
  __syncthreads();   // B2
  if (t < 64) svec[t] = sigf(adj[t] + bl2[0]);
  __syncthreads();   // B2'

  // ---------- PASS M ----------
  floatx4 am[2][4];
  #pragma unroll
  for (int rt = 0; rt < 2; ++rt)
    #pragma unroll
    for (int ct = 0; ct < 4; ++ct) am[rt][ct] = (floatx4){0.f,0.f,0.f,0.f};
  #pragma unroll
  for (int kp = 0; kp < 2; ++kp) {
    uint4 bb[2][4];
    #pragma unroll
    for (int k2 = 0; k2 < 2; ++k2)
      #pragma unroll
      for (int ct = 0; ct < 4; ++ct)
        bb[k2][ct] = *(const uint4*)(wm + colg[ct]*64 + (kp*2 + k2)*16 + q*4);
    #pragma unroll
    for (int k2 = 0; k2 < 2; ++k2)
      #pragma unroll
      for (int rt = 0; rt < 2; ++rt)
        if (rt < nvt) {
          uint4 a = *(const uint4*)&e_s[arowi[rt]*68 + (kp*2 + k2)*16 + q*4];
          #pragma unroll
          for (int ct = 0; ct < 4; ++ct)
            am[rt][ct] = __builtin_amdgcn_mfma_f32_16x16x32_bf16(as_s8(a), as_s8(bb[k2][ct]), am[rt][ct], 0, 0, 0);
        }
  }

  // M epilogue
  {
    float bMv[4];
    #pragma unroll
    for (int ct = 0; ct < 4; ++ct) bMv[ct] = bM_s[colg[ct]];
    float colsum[4] = {0.f,0.f,0.f,0.f};
    #pragma unroll
    for (int rt = 0; rt < 2; ++rt) {
      if (rt < nvt) {
        #pragma unroll
        for (int ct = 0; ct < 4; ++ct) {
          #pragma unroll
          for (int r = 0; r < 4; ++r) {
            int lrow = rh2*32 + rt*16 + q*4 + r;
            float amv = a_m[(size_t)(b*128 + row0 + lrow)*128 + colg[ct]];
            float mv = fmaxf(am[rt][ct][r] + amv + bMv[ct], 0.f);
            float sc = (lrow < vnl) ? svec[lrow] : 0.f;
            mv *= sc;
            m16[lrow*136 + colg[ct]] = bf16_1(mv);
            colsum[ct] += mv;
          }
        }
      }
    }
    #pragma unroll
    for (int ct = 0; ct < 4; ++ct) {
      float v = colsum[ct];
      v += __shfl_xor(v, 16);
      v += __shfl_xor(v, 32);
      if (lane < 16) atomicAdd(&msum[colg[ct]], v);
    }
  }
  __syncthreads();   // B3
  if (t < 128) atomicAdd(&ms[(size_t)(b*128 + j)*128 + t], msum[t]);

  // ---------- PASS U ----------
  floatx4 au[2][4];
  #pragma unroll
  for (int rt = 0; rt < 2; ++rt)
    #pragma unroll
    for (int ct = 0; ct < 4; ++ct) au[rt][ct] = (floatx4){0.f,0.f,0.f,0.f};
  #pragma unroll
  for (int kp = 0; kp < 2; ++kp) {
    uint4 bb[2][4];
    #pragma unroll
    for (int k2 = 0; k2 < 2; ++k2)
      #pragma unroll
      for (int ct = 0; ct < 4; ++ct)
        bb[k2][ct] = *(const uint4*)(wue + colg[ct]*64 + (kp*2 + k2)*16 + q*4);
    #pragma unroll
    for (int k2 = 0; k2 < 2; ++k2)
      #pragma unroll
      for (int rt = 0; rt < 2; ++rt)
        if (rt < nvt) {
          uint4 a = *(const uint4*)&e_s[arowi[rt]*68 + (kp*2 + k2)*16 + q*4];
          #pragma unroll
          for (int ct = 0; ct < 4; ++ct)
            au[rt][ct] = __builtin_amdgcn_mfma_f32_16x16x32_bf16(as_s8(a), as_s8(bb[k2][ct]), au[rt][ct], 0, 0, 0);
        }
  }
  #pragma unroll
  for (int kp = 0; kp < 2; ++kp) {
    uint4 bb[2][4];
    #pragma unroll
    for (int k2 = 0; k2 < 2; ++k2)
      #pragma unroll
      for (int ct = 0; ct < 4; ++ct)
        bb[k2][ct] = *(const uint4*)(wum + colg[ct]*64 + (kp*2 + k2)*16 + q*4);
    #pragma unroll
    for (int k2 = 0; k2 < 2; ++k2)
      #pragma unroll
      for (int rt = 0; rt < 2; ++rt)
        if (rt < nvt) {
          uint4 a = *(const uint4*)&m_a[arowi[rt]*68 + (kp*2 + k2)*16 + q*4];
          #pragma unroll
          for (int ct = 0; ct < 4; ++ct)
            au[rt][ct] = __builtin_amdgcn_mfma_f32_16x16x32_bf16(as_s8(a), as_s8(bb[k2][ct]), au[rt][ct], 0, 0, 0);
        }
  }
  __syncthreads();   // B4

  {
    float buv[4];
    #pragma unroll
    for (int ct = 0; ct < 4; ++ct) buv[ct] = bu_s[colg[ct]];
    #pragma unroll
    for (int rt = 0; rt < 2; ++rt)
      if (rt < nvt)
        #pragma unroll
        for (int ct = 0; ct < 4; ++ct)
          #pragma unroll
          for (int r = 0; r < 4; ++r) {
            int lrow = rh2*32 + rt*16 + q*4 + r;
            m16[lrow*136 + colg[ct]] = bf16_1(fmaxf(au[rt][ct][r] + buv[ct], 0.f));
          }
  }
  __syncthreads();   // B5
  #pragma unroll
  for (int it = 0; it < 16; ++it) {
    int f = it*256 + t;
    int lr = f >> 6, c2 = f & 63;
    if (row0 + lr < vn) eblk[(size_t)(row0 + lr)*64 + c2] = m_a[lr*68 + c2];
  }
}

// ---------- MFMA readout, both GEMMs on matrix cores ----------
__global__ __launch_bounds__(256,4) void readout_mfma(
  const unsigned* __restrict__ eg,
  const unsigned* __restrict__ wr1T,
  const unsigned* __restrict__ wr2T,
  const float* __restrict__ br1, const float* __restrict__ br2,
  const int* __restrict__ event_nums, float* __restrict__ out)
{
  __shared__ unsigned f_s[64*132];
  __shared__ int iu_s[64], ju_s[64];
  unsigned short* h16 = (unsigned short*)f_s;

  const int t = threadIdx.x;
  const int b = blockIdx.x / 127, pb = blockIdx.x % 127;
  const int vn = event_nums[b];

  if (t < 64) {
    int p = pb*64 + t;
    float disc = (float)((2*NN-1)*(2*NN-1) - 8*p);
    int iu = (int)(((float)(2*NN-1) - sqrtf(disc)) * 0.5f);
    if (iu < 0) iu = 0; if (iu > NN-2) iu = NN-2;
    while (iu < NN-2 && ((iu+1)*(2*NN-2-iu))/2 <= p) ++iu;
    while (iu > 0 && (iu*(2*NN-1-iu))/2 > p) --iu;
    int ju = p - (iu*(2*NN-1-iu))/2 + iu + 1;
    iu_s[t] = iu; ju_s[t] = ju;
  }
  __syncthreads();

  #pragma unroll
  for (int it = 0; it < 32; ++it) {
    int f = it*256 + t;
    int pr = f >> 7, w = f & 127;
    int side = w >> 6, k2l = w & 63;
    int iu = iu_s[pr], ju = ju_s[pr];
    size_t base = side ? (((size_t)(b*128 + iu))*128 + ju)*64
                       : (((size_t)(b*128 + ju))*128 + iu)*64;
    f_s[pr*132 + w] = eg[base + k2l];
  }
  __syncthreads();

  const int lane = t & 63, wv = t >> 6;
  const int q = lane >> 4, n = lane & 15;
  int colg[4];
  #pragma unroll
  for (int ct = 0; ct < 4; ++ct) colg[ct] = wv*64 + ct*16 + n;

  floatx4 acc[4][4];
  #pragma unroll
  for (int rt = 0; rt < 4; ++rt)
    #pragma unroll
    for (int ct = 0; ct < 4; ++ct) acc[rt][ct] = (floatx4){0.f,0.f,0.f,0.f};

  #pragma unroll
  for (int kb = 0; kb < 8; ++kb) {
    uint4 bb[4];
    #pragma unroll
    for (int ct = 0; ct < 4; ++ct) bb[ct] = *(const uint4*)(wr1T + (size_t)colg[ct]*128 + kb*16 + q*4);
    #pragma unroll
    for (int rt = 0; rt < 4; ++rt) {
      uint4 a = *(const uint4*)&f_s[(rt*16 + n)*132 + kb*16 + q*4];
      #pragma unroll
      for (int ct = 0; ct < 4; ++ct)
        acc[rt][ct] = __builtin_amdgcn_mfma_f32_16x16x32_bf16(as_s8(a), as_s8(bb[ct]), acc[rt][ct], 0, 0, 0);
    }
  }
  __syncthreads();

  {
    float brv[4];
    #pragma unroll
    for (int ct = 0; ct < 4; ++ct) brv[ct] = br1[colg[ct]];
    #pragma unroll
    for (int rt = 0; rt < 4; ++rt)
      #pragma unroll
      for (int ct = 0; ct < 4; ++ct)
        #pragma unroll
        for (int r = 0; r < 4; ++r) {
          int pr = rt*16 + q*4 + r;
          h16[pr*264 + colg[ct]] = bf16_1(fmaxf(acc[rt][ct][r] + brv[ct], 0.f));
        }
  }
  __syncthreads();

  floatx4 acc2 = (floatx4){0.f,0.f,0.f,0.f};
  #pragma unroll
  for (int kb = 0; kb < 8; ++kb) {
    uint4 bb = *(const uint4*)(wr2T + n*128 + kb*16 + q*4);
    uint4 a  = *(const uint4*)&f_s[(wv*16 + n)*132 + kb*16 + q*4];
    acc2 = __builtin_amdgcn_mfma_f32_16x16x32_bf16(as_s8(a), as_s8(bb), acc2, 0, 0, 0);
  }

  if (n < 10) {
    float bias = br2[n];
    #pragma unroll
    for (int r = 0; r < 4; ++r) {
      int pr = wv*16 + q*4 + r;
      int iu = iu_s[pr], ju = ju_s[pr];
      if (ju < vn) {
        int idx = iu*vn - (iu*(iu+1))/2 + (ju - iu - 1);
        out[(((size_t)b*5 + (n>>1))*PP + idx)*2 + (n&1)] = acc2[r] + bias;
      }
    }
  }
}

extern "C" void kernel_launch(void* const* d_in, const int* in_sizes, int n_in,
                              void* d_out, int out_size, void* d_ws, size_t ws_size,
                              hipStream_t stream) {
  const int*   edge_ids      = (const int*)d_in[0];
  const float* node_features = (const float*)d_in[1];
  const int*   event_nums    = (const int*)d_in[3];
  const float* emb  = (const float*)d_in[4];
  const float* Wl_e = (const float*)d_in[5];
  const float* Wl_w = (const float*)d_in[6];
  const float* Wl_v = (const float*)d_in[7];
  const float* bl1  = (const float*)d_in[8];
  const float* wl2  = (const float*)d_in[9];
  const float* bl2  = (const float*)d_in[10];
  const float* Wm_w = (const float*)d_in[11];
  const float* Wm_v = (const float*)d_in[12];
  const float* Wm_e = (const float*)d_in[13];
  const float* bm   = (const float*)d_in[14];
  const float* Wu_e = (const float*)d_in[15];
  const float* Wu_m = (const float*)d_in[16];
  const float* bu   = (const float*)d_in[17];
  const float* W_ih = (const float*)d_in[18];
  const float* W_hh = (const float*)d_in[19];
  const float* b_ih = (const float*)d_in[20];
  const float* b_hh = (const float*)d_in[21];
  const float* Wr1  = (const float*)d_in[22];
  const float* br1  = (const float*)d_in[23];
  const float* Wr2  = (const float*)d_in[24];
  const float* br2  = (const float*)d_in[25];

  const size_t SZ_E = (size_t)134217728;       // B*N*N*64 u32
  const size_t SZ_S = (size_t)2097152;         // B*N*128 f32
  const size_t SZ_W = (size_t)131072;          // 32768 u32
  const size_t SZ_W2 = (size_t)8192;           // 2048 u32
  const size_t SZ_TAB = (size_t)2048;          // 512 f32 each
  const size_t need = SZ_E + 6*SZ_S + 2*SZ_W + SZ_W2 + 3*SZ_TAB;

  hipMemsetAsync(d_out, 0, (size_t)out_size * sizeof(float), stream);
  if (ws_size < need) return;

  char* w = (char*)d_ws;
  unsigned* eg   = (unsigned*)w; w += SZ_E;
  float* h_ws = (float*)w; w += SZ_S;
  float* a_l  = (float*)w; w += SZ_S;
  float* b_l  = (float*)w; w += SZ_S;
  float* a_m  = (float*)w; w += SZ_S;
  float* b_m  = (float*)w; w += SZ_S;
  float* ms   = (float*)w; w += SZ_S;
  unsigned* wT   = (unsigned*)w; w += SZ_W;
  unsigned* wr1T = (unsigned*)w; w += SZ_W;
  unsigned* wr2T = (unsigned*)w; w += SZ_W2;
  float* embZ = (float*)w; w += SZ_TAB;
  float* embM = (float*)w; w += SZ_TAB;
  float* embU = (float*)w; w += SZ_TAB;

  hipLaunchKernelGGL(conv_w_kernel, dim3(256), dim3(256), 0, stream,
      Wl_e, Wm_e, Wu_e, Wu_m, Wr1, Wr2, emb, wT, wr1T, wr2T, embZ, embM, embU);

  hipLaunchKernelGGL(gru_proj_kernel, dim3(1024), dim3(256), 0, stream,
      0, ms, node_features, h_ws, W_ih, W_hh, b_ih, b_hh,
      Wl_w, Wl_v, Wm_w, Wm_v, event_nums, a_l, b_l, a_m, b_m);

  for (int r = 0; r < 3; ++r) {
    hipMemsetAsync(ms, 0, SZ_S, stream);
    if (r == 0) {
      hipLaunchKernelGGL(edge_round_first, dim3(8192), dim3(256), 0, stream,
          eg, wT, edge_ids, embZ, embM, embU,
          a_l, b_l, a_m, b_m, bl1, wl2, bl2, bm, bu, event_nums, ms);
    } else {
      hipLaunchKernelGGL(edge_round_rest, dim3(8192), dim3(256), 0, stream,
          eg, wT, a_l, b_l, a_m, b_m, bl1, wl2, bl2, bm, bu, event_nums, ms);
    }
    if (r < 2) {
      const float* hin = (r == 0) ? node_features : h_ws;
      hipLaunchKernelGGL(gru_proj_kernel, dim3(1024), dim3(256), 0, stream,
          1, ms, hin, h_ws, W_ih, W_hh, b_ih, b_hh,
          Wl_w, Wl_v, Wm_w, Wm_v, event_nums, a_l, b_l, a_m, b_m);
    }
  }

  hipLaunchKernelGGL(readout_mfma, dim3(BB*127), dim3(256), 0, stream,
      eg, wr1T, wr2T, br1, br2, event_nums, (float*)d_out);
}